// Round 1
// baseline (494.508 us; speedup 1.0000x reference)
//
#include <hip/hip_runtime.h>
#include <hip/hip_bf16.h>
#include <math.h>

#define NEG_SLOPE 0.2f

__device__ __forceinline__ float lrelu(float x) { return x > 0.f ? x : NEG_SLOPE * x; }

// ------------------------------------------------------------------
// Tiled f32 GEMM: C[M,Nc] = A[M,K] @ B[K,Nc], row-major.
// 64x64 tile, BK=16, 256 threads, 4x4 micro-tile per thread.
// Requires: Nc % 64 == 0, K % 16 == 0 (M guarded).
// ------------------------------------------------------------------
#define BM 64
#define BN 64
#define BK 16
__global__ __launch_bounds__(256) void gemm_f32(const float* __restrict__ A,
                                                const float* __restrict__ B,
                                                float* __restrict__ C,
                                                int M, int Nc, int K)
{
    __shared__ float As[BK][BM];
    __shared__ float Bs[BK][BN];
    const int tid = threadIdx.x;
    const int brow = blockIdx.y * BM;
    const int bcol = blockIdx.x * BN;
    const int tx = tid & 15;        // 0..15 -> 4 cols each
    const int ty = tid >> 4;        // 0..15 -> 4 rows each

    float acc[4][4];
#pragma unroll
    for (int i = 0; i < 4; ++i)
#pragma unroll
        for (int j = 0; j < 4; ++j) acc[i][j] = 0.f;

    for (int k0 = 0; k0 < K; k0 += BK) {
        { // load A tile: 64 rows x 16 k, float4 per thread
            int r = tid >> 2;
            int kk = (tid & 3) * 4;
            int gr = brow + r;
            float4 v = make_float4(0.f, 0.f, 0.f, 0.f);
            if (gr < M) v = *reinterpret_cast<const float4*>(A + (size_t)gr * K + k0 + kk);
            As[kk + 0][r] = v.x; As[kk + 1][r] = v.y; As[kk + 2][r] = v.z; As[kk + 3][r] = v.w;
        }
        { // load B tile: 16 k x 64 cols, float4 per thread
            int kk = tid >> 4;
            int c = (tid & 15) * 4;
            float4 v = *reinterpret_cast<const float4*>(B + (size_t)(k0 + kk) * Nc + bcol + c);
            *reinterpret_cast<float4*>(&Bs[kk][c]) = v;
        }
        __syncthreads();
#pragma unroll
        for (int kk = 0; kk < BK; ++kk) {
            float4 av = *reinterpret_cast<const float4*>(&As[kk][ty * 4]);
            float4 bv = *reinterpret_cast<const float4*>(&Bs[kk][tx * 4]);
            float a[4] = {av.x, av.y, av.z, av.w};
            float b[4] = {bv.x, bv.y, bv.z, bv.w};
#pragma unroll
            for (int i = 0; i < 4; ++i)
#pragma unroll
                for (int j = 0; j < 4; ++j) acc[i][j] = fmaf(a[i], b[j], acc[i][j]);
        }
        __syncthreads();
    }
#pragma unroll
    for (int i = 0; i < 4; ++i) {
        int gr = brow + ty * 4 + i;
        if (gr < M) {
            float4 v = make_float4(acc[i][0], acc[i][1], acc[i][2], acc[i][3]);
            *reinterpret_cast<float4*>(C + (size_t)gr * Nc + bcol + tx * 4) = v;
        }
    }
}

// ------------------------------------------------------------------
// Attention scores: a_s[nd*H+h] = sum_c xl[nd,h,c]*att_s[h,c]; same for a_d.
// One 64-lane wave per (node, head).
// ------------------------------------------------------------------
__global__ __launch_bounds__(256) void attn_scores(const float* __restrict__ xl,
                                                   const float* __restrict__ att_s,
                                                   const float* __restrict__ att_d,
                                                   float* __restrict__ a_s,
                                                   float* __restrict__ a_d,
                                                   int NH, int H, int C)
{
    int wid = (blockIdx.x * 256 + threadIdx.x) >> 6;
    int lane = threadIdx.x & 63;
    if (wid >= NH) return;
    int h = wid % H;
    const float* row = xl + (size_t)wid * C;   // [N,H,C] flattened: (nd*H+h)*C
    float ss = 0.f, sd = 0.f;
    for (int c = lane; c < C; c += 64) {
        float v = row[c];
        ss = fmaf(v, att_s[h * C + c], ss);
        sd = fmaf(v, att_d[h * C + c], sd);
    }
#pragma unroll
    for (int o = 32; o > 0; o >>= 1) {
        ss += __shfl_down(ss, o);
        sd += __shfl_down(sd, o);
    }
    if (lane == 0) { a_s[wid] = ss; a_d[wid] = sd; }
}

// ------------------------------------------------------------------
// CSR build: count, scan, scatter. Edges: e<E from edge_index, e>=E self-loops.
// ------------------------------------------------------------------
__global__ __launch_bounds__(256) void count_deg(const int* __restrict__ ei, int E, int E2,
                                                 int* __restrict__ counts)
{
    int e = blockIdx.x * 256 + threadIdx.x;
    if (e >= E2) return;
    int dd = (e < E) ? ei[E + e] : (e - E);
    atomicAdd(&counts[dd], 1);
}

__global__ __launch_bounds__(256) void scan_excl(const int* __restrict__ counts,
                                                 int* __restrict__ offsets, int n)
{
    __shared__ int sh[256];
    __shared__ int running;
    int tid = threadIdx.x;
    if (tid == 0) running = 0;
    __syncthreads();
    for (int base = 0; base < n; base += 256) {
        int i = base + tid;
        int v = (i < n) ? counts[i] : 0;
        sh[tid] = v;
        __syncthreads();
#pragma unroll
        for (int off = 1; off < 256; off <<= 1) {
            int t = (tid >= off) ? sh[tid - off] : 0;
            __syncthreads();
            sh[tid] += t;
            __syncthreads();
        }
        int incl = sh[tid];
        if (i < n) offsets[i] = running + (incl - v);
        __syncthreads();                 // everyone has read `running`
        if (tid == 255) running += sh[255];
        __syncthreads();
    }
    if (tid == 0) offsets[n] = running;
}

__global__ __launch_bounds__(256) void scatter_csr(const int* __restrict__ ei, int E, int E2,
                                                   const int* __restrict__ offsets,
                                                   int* __restrict__ cursor,
                                                   int* __restrict__ csr_src)
{
    int e = blockIdx.x * 256 + threadIdx.x;
    if (e >= E2) return;
    int s, dd;
    if (e < E) { s = ei[e]; dd = ei[E + e]; }
    else       { s = e - E; dd = e - E; }
    int pos = offsets[dd] + atomicAdd(&cursor[dd], 1);
    csr_src[pos] = s;
}

// ------------------------------------------------------------------
// Layer-1 aggregation (H=4, C=256). One block (256 thr) per dst node.
// Fused segment-softmax (in-wave) + weighted gather-sum + bias + relu.
// ------------------------------------------------------------------
__global__ __launch_bounds__(256) void agg_h4(const float* __restrict__ xl,
                                              const float* __restrict__ a_s,
                                              const float* __restrict__ a_d,
                                              const int* __restrict__ offsets,
                                              const int* __restrict__ csr_src,
                                              const float* __restrict__ bias,
                                              float* __restrict__ outbuf)
{
    const int dst = blockIdx.x;
    const int t = threadIdx.x;
    const int o0 = offsets[dst];
    const int deg = offsets[dst + 1] - o0;
    __shared__ float sh_m[4], sh_d[4];

    if (t < 64) {   // wave 0: per-head max & denom
        int h = t & 3;
        float adh = a_d[dst * 4 + h];
        float m = -1e30f;
        for (int i = (t >> 2); i < deg; i += 16) {
            int s = csr_src[o0 + i];
            m = fmaxf(m, lrelu(a_s[s * 4 + h] + adh));
        }
#pragma unroll
        for (int o = 4; o < 64; o <<= 1) m = fmaxf(m, __shfl_xor(m, o));
        float sum = 0.f;
        for (int i = (t >> 2); i < deg; i += 16) {
            int s = csr_src[o0 + i];
            sum += __expf(lrelu(a_s[s * 4 + h] + adh) - m);
        }
#pragma unroll
        for (int o = 4; o < 64; o <<= 1) sum += __shfl_xor(sum, o);
        if (t < 4) { sh_m[t] = m; sh_d[t] = sum; }
    }
    __syncthreads();

    const int c4 = t * 4;           // channel base in [0,1024)
    const int h = t >> 6;           // head
    const float m = sh_m[h];
    const float inv_d = 1.f / sh_d[h];
    const float adh = a_d[dst * 4 + h];
    float4 acc = make_float4(0.f, 0.f, 0.f, 0.f);
    for (int i = 0; i < deg; ++i) {
        int s = csr_src[o0 + i];
        float alpha = __expf(lrelu(a_s[s * 4 + h] + adh) - m) * inv_d;
        float4 v = *reinterpret_cast<const float4*>(xl + (size_t)s * 1024 + c4);
        acc.x = fmaf(alpha, v.x, acc.x);
        acc.y = fmaf(alpha, v.y, acc.y);
        acc.z = fmaf(alpha, v.z, acc.z);
        acc.w = fmaf(alpha, v.w, acc.w);
    }
    float4 b = *reinterpret_cast<const float4*>(bias + c4);
    float4 r;
    r.x = fmaxf(acc.x + b.x, 0.f);
    r.y = fmaxf(acc.y + b.y, 0.f);
    r.z = fmaxf(acc.z + b.z, 0.f);
    r.w = fmaxf(acc.w + b.w, 0.f);
    *reinterpret_cast<float4*>(outbuf + (size_t)dst * 1024 + c4) = r;
}

// ------------------------------------------------------------------
// Layer-2 aggregation (H=1, C=256). One wave per dst node.
// ------------------------------------------------------------------
__global__ __launch_bounds__(64) void agg_h1(const float* __restrict__ xl,
                                             const float* __restrict__ a_s,
                                             const float* __restrict__ a_d,
                                             const int* __restrict__ offsets,
                                             const int* __restrict__ csr_src,
                                             const float* __restrict__ bias,
                                             float* __restrict__ outbuf)
{
    const int dst = blockIdx.x;
    const int lane = threadIdx.x;
    const int o0 = offsets[dst];
    const int deg = offsets[dst + 1] - o0;
    const float ad = a_d[dst];

    float m = -1e30f;
    for (int i = lane; i < deg; i += 64)
        m = fmaxf(m, lrelu(a_s[csr_src[o0 + i]] + ad));
#pragma unroll
    for (int o = 1; o < 64; o <<= 1) m = fmaxf(m, __shfl_xor(m, o));
    float sum = 0.f;
    for (int i = lane; i < deg; i += 64)
        sum += __expf(lrelu(a_s[csr_src[o0 + i]] + ad) - m);
#pragma unroll
    for (int o = 1; o < 64; o <<= 1) sum += __shfl_xor(sum, o);
    const float inv_d = 1.f / sum;

    const int c4 = lane * 4;
    float4 acc = make_float4(0.f, 0.f, 0.f, 0.f);
    for (int i = 0; i < deg; ++i) {
        int s = csr_src[o0 + i];
        float alpha = __expf(lrelu(a_s[s] + ad) - m) * inv_d;
        float4 v = *reinterpret_cast<const float4*>(xl + (size_t)s * 256 + c4);
        acc.x = fmaf(alpha, v.x, acc.x);
        acc.y = fmaf(alpha, v.y, acc.y);
        acc.z = fmaf(alpha, v.z, acc.z);
        acc.w = fmaf(alpha, v.w, acc.w);
    }
    float4 b = *reinterpret_cast<const float4*>(bias + c4);
    float4 r;
    r.x = fmaxf(acc.x + b.x, 0.f);
    r.y = fmaxf(acc.y + b.y, 0.f);
    r.z = fmaxf(acc.z + b.z, 0.f);
    r.w = fmaxf(acc.w + b.w, 0.f);
    *reinterpret_cast<float4*>(outbuf + (size_t)dst * 256 + c4) = r;
}

// ------------------------------------------------------------------
// Mean pool: sum columns into meanv (zeroed); divide in final kernel.
// ------------------------------------------------------------------
__global__ __launch_bounds__(256) void mean_pool(const float* __restrict__ h2,
                                                 float* __restrict__ meanv, int N)
{
    int c = threadIdx.x;
    float s = 0.f;
    for (int r = blockIdx.x; r < N; r += gridDim.x)
        s += h2[(size_t)r * 256 + c];
    atomicAdd(&meanv[c], s);
}

__global__ __launch_bounds__(64) void final_k(const float* __restrict__ meanv,
                                              const float* __restrict__ Wc,
                                              const float* __restrict__ bc,
                                              float* __restrict__ out, int N, int NCLS)
{
    int k = threadIdx.x;
    if (k >= NCLS) return;
    float invN = 1.f / (float)N;
    float s = 0.f;
    for (int c = 0; c < 256; ++c)
        s = fmaf(meanv[c] * invN, Wc[c * NCLS + k], s);
    out[k] = s + bc[k];
}

// ------------------------------------------------------------------
extern "C" void kernel_launch(void* const* d_in, const int* in_sizes, int n_in,
                              void* d_out, int out_size, void* d_ws, size_t ws_size,
                              hipStream_t stream)
{
    const float* x   = (const float*)d_in[0];
    const int*   ei  = (const int*)d_in[1];
    const float* W1  = (const float*)d_in[2];
    const float* as1 = (const float*)d_in[3];
    const float* ad1 = (const float*)d_in[4];
    const float* b1  = (const float*)d_in[5];
    const float* W2  = (const float*)d_in[6];
    const float* as2 = (const float*)d_in[7];
    const float* ad2 = (const float*)d_in[8];
    const float* b2  = (const float*)d_in[9];
    const float* Wc  = (const float*)d_in[10];
    const float* bc  = (const float*)d_in[11];
    float* out = (float*)d_out;

    const int D = 128, H = 4, C = 256, HC = 1024;
    const int N = in_sizes[0] / D;          // 10000
    const int E = in_sizes[1] / 2;          // 160000
    const int E2 = E + N;                   // + self loops
    const int NCLS = in_sizes[11];          // 10

    char* ws = (char*)d_ws;
    size_t woff = 0;
    auto take = [&](size_t bytes) -> char* {
        char* p = ws + woff;
        woff += (bytes + 255) & ~(size_t)255;
        return p;
    };
    float* bufA   = (float*)take((size_t)N * HC * 4);  // xl1; later xl2 + h2
    float* h1     = (float*)take((size_t)N * HC * 4);
    float* a_s1   = (float*)take((size_t)N * H * 4);
    float* a_d1   = (float*)take((size_t)N * H * 4);
    float* a_s2   = (float*)take((size_t)N * 4);
    float* a_d2   = (float*)take((size_t)N * 4);
    int*   counts = (int*)take((size_t)N * 4);
    int*   cursor = (int*)take((size_t)N * 4);
    int*   offs   = (int*)take((size_t)(N + 1) * 4);
    int*   csrsrc = (int*)take((size_t)E2 * 4);
    float* meanv  = (float*)take(256 * 4);

    float* xl1 = bufA;
    float* xl2 = bufA;                       // alias: xl1 dead after agg_h4
    float* h2  = bufA + (size_t)N * C;       // disjoint from xl2

    hipMemsetAsync(counts, 0, (size_t)N * 4, stream);
    hipMemsetAsync(cursor, 0, (size_t)N * 4, stream);
    hipMemsetAsync(meanv, 0, 256 * 4, stream);

    // Layer 1
    dim3 g1(HC / BN, (N + BM - 1) / BM);
    gemm_f32<<<g1, 256, 0, stream>>>(x, W1, xl1, N, HC, D);
    attn_scores<<<(N * H + 3) / 4, 256, 0, stream>>>(xl1, as1, ad1, a_s1, a_d1, N * H, H, C);
    count_deg<<<(E2 + 255) / 256, 256, 0, stream>>>(ei, E, E2, counts);
    scan_excl<<<1, 256, 0, stream>>>(counts, offs, N);
    scatter_csr<<<(E2 + 255) / 256, 256, 0, stream>>>(ei, E, E2, offs, cursor, csrsrc);
    agg_h4<<<N, 256, 0, stream>>>(xl1, a_s1, a_d1, offs, csrsrc, b1, h1);

    // Layer 2
    dim3 g2(C / BN, (N + BM - 1) / BM);
    gemm_f32<<<g2, 256, 0, stream>>>(h1, W2, xl2, N, C, HC);
    attn_scores<<<(N + 3) / 4, 256, 0, stream>>>(xl2, as2, ad2, a_s2, a_d2, N, 1, C);
    agg_h1<<<N, 64, 0, stream>>>(xl2, a_s2, a_d2, offs, csrsrc, b2, h2);

    // Pool + classifier
    mean_pool<<<40, 256, 0, stream>>>(h2, meanv, N);
    final_k<<<1, 64, 0, stream>>>(meanv, Wc, bc, out, N, NCLS);
}

// Round 2
// 360.449 us; speedup vs baseline: 1.3719x; 1.3719x over previous
//
#include <hip/hip_runtime.h>
#include <hip/hip_bf16.h>
#include <math.h>

#define NEG_SLOPE 0.2f

typedef __attribute__((ext_vector_type(8))) short short8;
typedef __attribute__((ext_vector_type(4))) float f32x4;

typedef __attribute__((address_space(1))) const void g_void;
typedef __attribute__((address_space(3))) void l_void;

__device__ __forceinline__ float lrelu(float x) { return x > 0.f ? x : NEG_SLOPE * x; }
__device__ __forceinline__ float bf2f(unsigned short u) { return __uint_as_float((unsigned)u << 16); }
__device__ __forceinline__ unsigned short f2bf(float f) {
    unsigned u = __float_as_uint(f);
    unsigned rounding = 0x7fff + ((u >> 16) & 1);
    return (unsigned short)((u + rounding) >> 16);
}

// ------------------------------------------------------------------
// Convert f32 -> bf16, zero-padding groups beyond n_valid4 (4 elems/thread).
// ------------------------------------------------------------------
__global__ __launch_bounds__(256) void convert_pad(const float* __restrict__ in,
                                                   unsigned short* __restrict__ out,
                                                   int n_valid4, int n_total4)
{
    int g = blockIdx.x * 256 + threadIdx.x;
    if (g >= n_total4) return;
    ushort4 o;
    if (g < n_valid4) {
        float4 v = *reinterpret_cast<const float4*>(in + (size_t)g * 4);
        o = make_ushort4(f2bf(v.x), f2bf(v.y), f2bf(v.z), f2bf(v.w));
    } else {
        o = make_ushort4(0, 0, 0, 0);
    }
    *reinterpret_cast<ushort4*>(out + (size_t)g * 4) = o;
}

// ------------------------------------------------------------------
// Transpose + convert: out[Cc][R] (bf16) = in[R][Cc]^T (f32).
// R, Cc multiples of 32. block (32,8), grid (Cc/32, R/32).
// ------------------------------------------------------------------
__global__ void transpose_cvt(const float* __restrict__ in, unsigned short* __restrict__ out,
                              int R, int Cc)
{
    __shared__ float tile[32][33];
    int c0 = blockIdx.x * 32, r0 = blockIdx.y * 32;
#pragma unroll
    for (int j = 0; j < 4; ++j)
        tile[threadIdx.y + j * 8][threadIdx.x] =
            in[(size_t)(r0 + threadIdx.y + j * 8) * Cc + c0 + threadIdx.x];
    __syncthreads();
#pragma unroll
    for (int j = 0; j < 4; ++j)
        out[(size_t)(c0 + threadIdx.y + j * 8) * R + r0 + threadIdx.x] =
            f2bf(tile[threadIdx.x][threadIdx.y + j * 8]);
}

// ------------------------------------------------------------------
// bf16 MFMA GEMM: C[M,Nc] = A[M,K] @ Bt[Nc,K]^T, all bf16, f32 accum.
// 128x128 tile, BK=64, 256 threads (4 waves, 2x2), 4x4 16x16x32 frags/wave.
// Staging: global_load_lds width 16, XOR-swizzled source (chunk ^= row&7);
// reads apply the same swizzle -> conflict-free ds_read_b128.
// Requires: M % 128 == 0 (padded), Nc % 128 == 0, K % 64 == 0.
// ------------------------------------------------------------------
__global__ __launch_bounds__(256) void gemm_bf16(const unsigned short* __restrict__ A,
                                                 const unsigned short* __restrict__ Bt,
                                                 unsigned short* __restrict__ C,
                                                 int M, int Nc, int K)
{
    __shared__ unsigned short sA[128 * 64];
    __shared__ unsigned short sB[128 * 64];
    const int tid = threadIdx.x;
    const int lane = tid & 63;
    const int w = tid >> 6;
    const int wr = w >> 1, wc = w & 1;
    const int m0 = blockIdx.y * 128;
    const int n0 = blockIdx.x * 128;

    f32x4 acc[4][4];
#pragma unroll
    for (int i = 0; i < 4; ++i)
#pragma unroll
        for (int j = 0; j < 4; ++j) acc[i][j] = (f32x4){0.f, 0.f, 0.f, 0.f};

    const int lrow = lane >> 3;               // row within 8-row group
    const int lchunk = (lane & 7) ^ lrow;     // swizzled source 16B-chunk

    for (int k0 = 0; k0 < K; k0 += 64) {
#pragma unroll
        for (int i = 0; i < 4; ++i) {
            int r0 = (w * 4 + i) * 8;
            const unsigned short* g = A + (size_t)(m0 + r0 + lrow) * K + k0 + lchunk * 8;
            __builtin_amdgcn_global_load_lds((g_void*)g, (l_void*)((char*)sA + r0 * 128), 16, 0, 0);
        }
#pragma unroll
        for (int i = 0; i < 4; ++i) {
            int r0 = (w * 4 + i) * 8;
            const unsigned short* g = Bt + (size_t)(n0 + r0 + lrow) * K + k0 + lchunk * 8;
            __builtin_amdgcn_global_load_lds((g_void*)g, (l_void*)((char*)sB + r0 * 128), 16, 0, 0);
        }
        __syncthreads();
#pragma unroll
        for (int kk = 0; kk < 2; ++kk) {
            short8 a[4], b[4];
#pragma unroll
            for (int i = 0; i < 4; ++i) {
                int r = wr * 64 + i * 16 + (lane & 15);
                int sw = (kk * 4 + (lane >> 4)) ^ (r & 7);
                a[i] = *reinterpret_cast<const short8*>(&sA[r * 64 + sw * 8]);
            }
#pragma unroll
            for (int j = 0; j < 4; ++j) {
                int r = wc * 64 + j * 16 + (lane & 15);
                int sw = (kk * 4 + (lane >> 4)) ^ (r & 7);
                b[j] = *reinterpret_cast<const short8*>(&sB[r * 64 + sw * 8]);
            }
#pragma unroll
            for (int i = 0; i < 4; ++i)
#pragma unroll
                for (int j = 0; j < 4; ++j)
                    acc[i][j] = __builtin_amdgcn_mfma_f32_16x16x32_bf16(a[i], b[j], acc[i][j], 0, 0, 0);
        }
        __syncthreads();
    }

#pragma unroll
    for (int i = 0; i < 4; ++i) {
        int row_b = m0 + wr * 64 + i * 16 + (lane >> 4) * 4;
#pragma unroll
        for (int j = 0; j < 4; ++j) {
            int col = n0 + wc * 64 + j * 16 + (lane & 15);
#pragma unroll
            for (int r = 0; r < 4; ++r)
                C[(size_t)(row_b + r) * Nc + col] = f2bf(acc[i][j][r]);
        }
    }
}

// ------------------------------------------------------------------
// Attention scores from bf16 xl (C=256 fixed): one wave per (node,head).
// ------------------------------------------------------------------
__global__ __launch_bounds__(256) void attn_scores(const unsigned short* __restrict__ xl,
                                                   const float* __restrict__ att_s,
                                                   const float* __restrict__ att_d,
                                                   float* __restrict__ a_s,
                                                   float* __restrict__ a_d,
                                                   int NH, int H)
{
    int wid = (blockIdx.x * 256 + threadIdx.x) >> 6;
    int lane = threadIdx.x & 63;
    if (wid >= NH) return;
    int h = wid % H;
    ushort4 v = *reinterpret_cast<const ushort4*>(xl + (size_t)wid * 256 + lane * 4);
    float4 vs = *reinterpret_cast<const float4*>(att_s + h * 256 + lane * 4);
    float4 vd = *reinterpret_cast<const float4*>(att_d + h * 256 + lane * 4);
    float x0 = bf2f(v.x), x1 = bf2f(v.y), x2 = bf2f(v.z), x3 = bf2f(v.w);
    float ss = x0 * vs.x + x1 * vs.y + x2 * vs.z + x3 * vs.w;
    float sd = x0 * vd.x + x1 * vd.y + x2 * vd.z + x3 * vd.w;
#pragma unroll
    for (int o = 32; o > 0; o >>= 1) {
        ss += __shfl_down(ss, o);
        sd += __shfl_down(sd, o);
    }
    if (lane == 0) { a_s[wid] = ss; a_d[wid] = sd; }
}

// ------------------------------------------------------------------
// CSR build (unchanged from round 1).
// ------------------------------------------------------------------
__global__ __launch_bounds__(256) void count_deg(const int* __restrict__ ei, int E, int E2,
                                                 int* __restrict__ counts)
{
    int e = blockIdx.x * 256 + threadIdx.x;
    if (e >= E2) return;
    int dd = (e < E) ? ei[E + e] : (e - E);
    atomicAdd(&counts[dd], 1);
}

__global__ __launch_bounds__(256) void scan_excl(const int* __restrict__ counts,
                                                 int* __restrict__ offsets, int n)
{
    __shared__ int sh[256];
    __shared__ int running;
    int tid = threadIdx.x;
    if (tid == 0) running = 0;
    __syncthreads();
    for (int base = 0; base < n; base += 256) {
        int i = base + tid;
        int v = (i < n) ? counts[i] : 0;
        sh[tid] = v;
        __syncthreads();
#pragma unroll
        for (int off = 1; off < 256; off <<= 1) {
            int t = (tid >= off) ? sh[tid - off] : 0;
            __syncthreads();
            sh[tid] += t;
            __syncthreads();
        }
        int incl = sh[tid];
        if (i < n) offsets[i] = running + (incl - v);
        __syncthreads();
        if (tid == 255) running += sh[255];
        __syncthreads();
    }
    if (tid == 0) offsets[n] = running;
}

__global__ __launch_bounds__(256) void scatter_csr(const int* __restrict__ ei, int E, int E2,
                                                   const int* __restrict__ offsets,
                                                   int* __restrict__ cursor,
                                                   int* __restrict__ csr_src)
{
    int e = blockIdx.x * 256 + threadIdx.x;
    if (e >= E2) return;
    int s, dd;
    if (e < E) { s = ei[e]; dd = ei[E + e]; }
    else       { s = e - E; dd = e - E; }
    int pos = offsets[dd] + atomicAdd(&cursor[dd], 1);
    csr_src[pos] = s;
}

// ------------------------------------------------------------------
// Layer-1 aggregation (H=4, C=256), bf16 gather -> bf16 out (+bias,relu).
// ------------------------------------------------------------------
__global__ __launch_bounds__(256) void agg_h4(const unsigned short* __restrict__ xl,
                                              const float* __restrict__ a_s,
                                              const float* __restrict__ a_d,
                                              const int* __restrict__ offsets,
                                              const int* __restrict__ csr_src,
                                              const float* __restrict__ bias,
                                              unsigned short* __restrict__ outb)
{
    const int dst = blockIdx.x;
    const int t = threadIdx.x;
    const int o0 = offsets[dst];
    const int deg = offsets[dst + 1] - o0;
    __shared__ float sh_m[4], sh_d[4];

    if (t < 64) {
        int h = t & 3;
        float adh = a_d[dst * 4 + h];
        float m = -1e30f;
        for (int i = (t >> 2); i < deg; i += 16) {
            int s = csr_src[o0 + i];
            m = fmaxf(m, lrelu(a_s[s * 4 + h] + adh));
        }
#pragma unroll
        for (int o = 4; o < 64; o <<= 1) m = fmaxf(m, __shfl_xor(m, o));
        float sum = 0.f;
        for (int i = (t >> 2); i < deg; i += 16) {
            int s = csr_src[o0 + i];
            sum += __expf(lrelu(a_s[s * 4 + h] + adh) - m);
        }
#pragma unroll
        for (int o = 4; o < 64; o <<= 1) sum += __shfl_xor(sum, o);
        if (t < 4) { sh_m[t] = m; sh_d[t] = sum; }
    }
    __syncthreads();

    const int c4 = t * 4;
    const int h = t >> 6;
    const float m = sh_m[h];
    const float inv_d = 1.f / sh_d[h];
    const float adh = a_d[dst * 4 + h];
    float ax = 0.f, ay = 0.f, az = 0.f, aw = 0.f;
    for (int i = 0; i < deg; ++i) {
        int s = csr_src[o0 + i];
        float alpha = __expf(lrelu(a_s[s * 4 + h] + adh) - m) * inv_d;
        ushort4 v = *reinterpret_cast<const ushort4*>(xl + (size_t)s * 1024 + c4);
        ax = fmaf(alpha, bf2f(v.x), ax);
        ay = fmaf(alpha, bf2f(v.y), ay);
        az = fmaf(alpha, bf2f(v.z), az);
        aw = fmaf(alpha, bf2f(v.w), aw);
    }
    float4 b = *reinterpret_cast<const float4*>(bias + c4);
    ushort4 r;
    r.x = f2bf(fmaxf(ax + b.x, 0.f));
    r.y = f2bf(fmaxf(ay + b.y, 0.f));
    r.z = f2bf(fmaxf(az + b.z, 0.f));
    r.w = f2bf(fmaxf(aw + b.w, 0.f));
    *reinterpret_cast<ushort4*>(outb + (size_t)dst * 1024 + c4) = r;
}

// ------------------------------------------------------------------
// Layer-2 aggregation (H=1, C=256), bf16 gather -> f32 out (+bias,relu).
// ------------------------------------------------------------------
__global__ __launch_bounds__(64) void agg_h1(const unsigned short* __restrict__ xl,
                                             const float* __restrict__ a_s,
                                             const float* __restrict__ a_d,
                                             const int* __restrict__ offsets,
                                             const int* __restrict__ csr_src,
                                             const float* __restrict__ bias,
                                             float* __restrict__ outb)
{
    const int dst = blockIdx.x;
    const int lane = threadIdx.x;
    const int o0 = offsets[dst];
    const int deg = offsets[dst + 1] - o0;
    const float ad = a_d[dst];

    float m = -1e30f;
    for (int i = lane; i < deg; i += 64)
        m = fmaxf(m, lrelu(a_s[csr_src[o0 + i]] + ad));
#pragma unroll
    for (int o = 1; o < 64; o <<= 1) m = fmaxf(m, __shfl_xor(m, o));
    float sum = 0.f;
    for (int i = lane; i < deg; i += 64)
        sum += __expf(lrelu(a_s[csr_src[o0 + i]] + ad) - m);
#pragma unroll
    for (int o = 1; o < 64; o <<= 1) sum += __shfl_xor(sum, o);
    const float inv_d = 1.f / sum;

    const int c4 = lane * 4;
    float ax = 0.f, ay = 0.f, az = 0.f, aw = 0.f;
    for (int i = 0; i < deg; ++i) {
        int s = csr_src[o0 + i];
        float alpha = __expf(lrelu(a_s[s] + ad) - m) * inv_d;
        ushort4 v = *reinterpret_cast<const ushort4*>(xl + (size_t)s * 256 + c4);
        ax = fmaf(alpha, bf2f(v.x), ax);
        ay = fmaf(alpha, bf2f(v.y), ay);
        az = fmaf(alpha, bf2f(v.z), az);
        aw = fmaf(alpha, bf2f(v.w), aw);
    }
    float4 b = *reinterpret_cast<const float4*>(bias + c4);
    float4 r;
    r.x = fmaxf(ax + b.x, 0.f);
    r.y = fmaxf(ay + b.y, 0.f);
    r.z = fmaxf(az + b.z, 0.f);
    r.w = fmaxf(aw + b.w, 0.f);
    *reinterpret_cast<float4*>(outb + (size_t)dst * 256 + c4) = r;
}

// ------------------------------------------------------------------
__global__ __launch_bounds__(256) void mean_pool(const float* __restrict__ h2,
                                                 float* __restrict__ meanv, int N)
{
    int c = threadIdx.x;
    float s = 0.f;
    for (int r = blockIdx.x; r < N; r += gridDim.x)
        s += h2[(size_t)r * 256 + c];
    atomicAdd(&meanv[c], s);
}

__global__ __launch_bounds__(64) void final_k(const float* __restrict__ meanv,
                                              const float* __restrict__ Wc,
                                              const float* __restrict__ bc,
                                              float* __restrict__ out, int N, int NCLS)
{
    int k = threadIdx.x;
    if (k >= NCLS) return;
    float invN = 1.f / (float)N;
    float s = 0.f;
    for (int c = 0; c < 256; ++c)
        s = fmaf(meanv[c] * invN, Wc[c * NCLS + k], s);
    out[k] = s + bc[k];
}

// ------------------------------------------------------------------
extern "C" void kernel_launch(void* const* d_in, const int* in_sizes, int n_in,
                              void* d_out, int out_size, void* d_ws, size_t ws_size,
                              hipStream_t stream)
{
    const float* x   = (const float*)d_in[0];
    const int*   ei  = (const int*)d_in[1];
    const float* W1  = (const float*)d_in[2];
    const float* as1 = (const float*)d_in[3];
    const float* ad1 = (const float*)d_in[4];
    const float* b1  = (const float*)d_in[5];
    const float* W2  = (const float*)d_in[6];
    const float* as2 = (const float*)d_in[7];
    const float* ad2 = (const float*)d_in[8];
    const float* b2  = (const float*)d_in[9];
    const float* Wc  = (const float*)d_in[10];
    const float* bc  = (const float*)d_in[11];
    float* out = (float*)d_out;

    const int D = 128, H = 4, C = 256, HC = 1024;
    const int N = in_sizes[0] / D;              // 10000
    const int E = in_sizes[1] / 2;              // 160000
    const int E2 = E + N;
    const int NCLS = in_sizes[11];
    const int Mpad = ((N + 127) / 128) * 128;   // 10112

    char* ws = (char*)d_ws;
    size_t woff = 0;
    auto take = [&](size_t bytes) -> char* {
        char* p = ws + woff;
        woff += (bytes + 255) & ~(size_t)255;
        return p;
    };
    unsigned short* x_bf  = (unsigned short*)take((size_t)Mpad * D * 2);
    unsigned short* w1t   = (unsigned short*)take((size_t)HC * D * 2);
    unsigned short* w2t   = (unsigned short*)take((size_t)C * HC * 2);
    unsigned short* xl1   = (unsigned short*)take((size_t)Mpad * HC * 2);
    unsigned short* h1    = (unsigned short*)take((size_t)Mpad * HC * 2);
    unsigned short* xl2   = (unsigned short*)take((size_t)Mpad * C * 2);
    float* h2     = (float*)take((size_t)N * C * 4);
    float* a_s1   = (float*)take((size_t)N * H * 4);
    float* a_d1   = (float*)take((size_t)N * H * 4);
    float* a_s2   = (float*)take((size_t)N * 4);
    float* a_d2   = (float*)take((size_t)N * 4);
    int*   counts = (int*)take((size_t)N * 4);
    int*   cursor = (int*)take((size_t)N * 4);
    int*   offs   = (int*)take((size_t)(N + 1) * 4);
    int*   csrsrc = (int*)take((size_t)E2 * 4);
    float* meanv  = (float*)take(256 * 4);

    hipMemsetAsync(counts, 0, (size_t)N * 4, stream);
    hipMemsetAsync(cursor, 0, (size_t)N * 4, stream);
    hipMemsetAsync(meanv, 0, 256 * 4, stream);
    if (Mpad > N)  // zero pad rows of h1 (agg only writes rows < N)
        hipMemsetAsync(h1 + (size_t)N * HC, 0, (size_t)(Mpad - N) * HC * 2, stream);

    // Input conversions
    convert_pad<<<(Mpad * D / 4 + 255) / 256, 256, 0, stream>>>(x, x_bf, N * D / 4, Mpad * D / 4);
    transpose_cvt<<<dim3(HC / 32, D / 32), dim3(32, 8), 0, stream>>>(W1, w1t, D, HC);
    transpose_cvt<<<dim3(C / 32, HC / 32), dim3(32, 8), 0, stream>>>(W2, w2t, HC, C);

    // CSR build
    count_deg<<<(E2 + 255) / 256, 256, 0, stream>>>(ei, E, E2, counts);
    scan_excl<<<1, 256, 0, stream>>>(counts, offs, N);
    scatter_csr<<<(E2 + 255) / 256, 256, 0, stream>>>(ei, E, E2, offs, cursor, csrsrc);

    // Layer 1
    gemm_bf16<<<dim3(HC / 128, Mpad / 128), 256, 0, stream>>>(x_bf, w1t, xl1, Mpad, HC, D);
    attn_scores<<<(N * H + 3) / 4, 256, 0, stream>>>(xl1, as1, ad1, a_s1, a_d1, N * H, H);
    agg_h4<<<N, 256, 0, stream>>>(xl1, a_s1, a_d1, offs, csrsrc, b1, h1);

    // Layer 2
    gemm_bf16<<<dim3(C / 128, Mpad / 128), 256, 0, stream>>>(h1, w2t, xl2, Mpad, C, HC);
    attn_scores<<<(N + 3) / 4, 256, 0, stream>>>(xl2, as2, ad2, a_s2, a_d2, N, 1);
    agg_h1<<<N, 64, 0, stream>>>(xl2, a_s2, a_d2, offs, csrsrc, b2, h2);

    // Pool + classifier
    mean_pool<<<40, 256, 0, stream>>>(h2, meanv, N);
    final_k<<<1, 64, 0, stream>>>(meanv, Wc, bc, out, N, NCLS);
}

// Round 3
// 305.516 us; speedup vs baseline: 1.6186x; 1.1798x over previous
//
#include <hip/hip_runtime.h>
#include <hip/hip_bf16.h>
#include <math.h>

#define NEG_SLOPE 0.2f

typedef __attribute__((ext_vector_type(8))) short short8;
typedef __attribute__((ext_vector_type(4))) float f32x4;

typedef __attribute__((address_space(1))) const void g_void;
typedef __attribute__((address_space(3))) void l_void;

__device__ __forceinline__ float lrelu(float x) { return x > 0.f ? x : NEG_SLOPE * x; }
__device__ __forceinline__ float bf2f(unsigned short u) { return __uint_as_float((unsigned)u << 16); }
__device__ __forceinline__ unsigned short f2bf(float f) {
    unsigned u = __float_as_uint(f);
    unsigned rounding = 0x7fff + ((u >> 16) & 1);
    return (unsigned short)((u + rounding) >> 16);
}

// ------------------------------------------------------------------
__global__ __launch_bounds__(256) void convert_pad(const float* __restrict__ in,
                                                   unsigned short* __restrict__ out,
                                                   int n_valid4, int n_total4)
{
    int g = blockIdx.x * 256 + threadIdx.x;
    if (g >= n_total4) return;
    ushort4 o;
    if (g < n_valid4) {
        float4 v = *reinterpret_cast<const float4*>(in + (size_t)g * 4);
        o = make_ushort4(f2bf(v.x), f2bf(v.y), f2bf(v.z), f2bf(v.w));
    } else {
        o = make_ushort4(0, 0, 0, 0);
    }
    *reinterpret_cast<ushort4*>(out + (size_t)g * 4) = o;
}

// ------------------------------------------------------------------
__global__ void transpose_cvt(const float* __restrict__ in, unsigned short* __restrict__ out,
                              int R, int Cc)
{
    __shared__ float tile[32][33];
    int c0 = blockIdx.x * 32, r0 = blockIdx.y * 32;
#pragma unroll
    for (int j = 0; j < 4; ++j)
        tile[threadIdx.y + j * 8][threadIdx.x] =
            in[(size_t)(r0 + threadIdx.y + j * 8) * Cc + c0 + threadIdx.x];
    __syncthreads();
#pragma unroll
    for (int j = 0; j < 4; ++j)
        out[(size_t)(c0 + threadIdx.y + j * 8) * R + r0 + threadIdx.x] =
            f2bf(tile[threadIdx.x][threadIdx.y + j * 8]);
}

// ------------------------------------------------------------------
// bf16 MFMA GEMM (unchanged from round 2): C = A @ Bt^T, 128x128, BK=64.
// ------------------------------------------------------------------
__global__ __launch_bounds__(256) void gemm_bf16(const unsigned short* __restrict__ A,
                                                 const unsigned short* __restrict__ Bt,
                                                 unsigned short* __restrict__ C,
                                                 int M, int Nc, int K)
{
    __shared__ unsigned short sA[128 * 64];
    __shared__ unsigned short sB[128 * 64];
    const int tid = threadIdx.x;
    const int lane = tid & 63;
    const int w = tid >> 6;
    const int wr = w >> 1, wc = w & 1;
    const int m0 = blockIdx.y * 128;
    const int n0 = blockIdx.x * 128;

    f32x4 acc[4][4];
#pragma unroll
    for (int i = 0; i < 4; ++i)
#pragma unroll
        for (int j = 0; j < 4; ++j) acc[i][j] = (f32x4){0.f, 0.f, 0.f, 0.f};

    const int lrow = lane >> 3;
    const int lchunk = (lane & 7) ^ lrow;

    for (int k0 = 0; k0 < K; k0 += 64) {
#pragma unroll
        for (int i = 0; i < 4; ++i) {
            int r0 = (w * 4 + i) * 8;
            const unsigned short* g = A + (size_t)(m0 + r0 + lrow) * K + k0 + lchunk * 8;
            __builtin_amdgcn_global_load_lds((g_void*)g, (l_void*)((char*)sA + r0 * 128), 16, 0, 0);
        }
#pragma unroll
        for (int i = 0; i < 4; ++i) {
            int r0 = (w * 4 + i) * 8;
            const unsigned short* g = Bt + (size_t)(n0 + r0 + lrow) * K + k0 + lchunk * 8;
            __builtin_amdgcn_global_load_lds((g_void*)g, (l_void*)((char*)sB + r0 * 128), 16, 0, 0);
        }
        __syncthreads();
#pragma unroll
        for (int kk = 0; kk < 2; ++kk) {
            short8 a[4], b[4];
#pragma unroll
            for (int i = 0; i < 4; ++i) {
                int r = wr * 64 + i * 16 + (lane & 15);
                int sw = (kk * 4 + (lane >> 4)) ^ (r & 7);
                a[i] = *reinterpret_cast<const short8*>(&sA[r * 64 + sw * 8]);
            }
#pragma unroll
            for (int j = 0; j < 4; ++j) {
                int r = wc * 64 + j * 16 + (lane & 15);
                int sw = (kk * 4 + (lane >> 4)) ^ (r & 7);
                b[j] = *reinterpret_cast<const short8*>(&sB[r * 64 + sw * 8]);
            }
#pragma unroll
            for (int i = 0; i < 4; ++i)
#pragma unroll
                for (int j = 0; j < 4; ++j)
                    acc[i][j] = __builtin_amdgcn_mfma_f32_16x16x32_bf16(a[i], b[j], acc[i][j], 0, 0, 0);
        }
        __syncthreads();
    }

#pragma unroll
    for (int i = 0; i < 4; ++i) {
        int row_b = m0 + wr * 64 + i * 16 + (lane >> 4) * 4;
#pragma unroll
        for (int j = 0; j < 4; ++j) {
            int col = n0 + wc * 64 + j * 16 + (lane & 15);
#pragma unroll
            for (int r = 0; r < 4; ++r)
                C[(size_t)(row_b + r) * Nc + col] = f2bf(acc[i][j][r]);
        }
    }
}

// ------------------------------------------------------------------
__global__ __launch_bounds__(256) void attn_scores(const unsigned short* __restrict__ xl,
                                                   const float* __restrict__ att_s,
                                                   const float* __restrict__ att_d,
                                                   float* __restrict__ a_s,
                                                   float* __restrict__ a_d,
                                                   int NH, int H)
{
    int wid = (blockIdx.x * 256 + threadIdx.x) >> 6;
    int lane = threadIdx.x & 63;
    if (wid >= NH) return;
    int h = wid % H;
    ushort4 v = *reinterpret_cast<const ushort4*>(xl + (size_t)wid * 256 + lane * 4);
    float4 vs = *reinterpret_cast<const float4*>(att_s + h * 256 + lane * 4);
    float4 vd = *reinterpret_cast<const float4*>(att_d + h * 256 + lane * 4);
    float x0 = bf2f(v.x), x1 = bf2f(v.y), x2 = bf2f(v.z), x3 = bf2f(v.w);
    float ss = x0 * vs.x + x1 * vs.y + x2 * vs.z + x3 * vs.w;
    float sd = x0 * vd.x + x1 * vd.y + x2 * vd.z + x3 * vd.w;
#pragma unroll
    for (int o = 32; o > 0; o >>= 1) {
        ss += __shfl_down(ss, o);
        sd += __shfl_down(sd, o);
    }
    if (lane == 0) { a_s[wid] = ss; a_d[wid] = sd; }
}

// ------------------------------------------------------------------
// CSR: count -> 2-kernel scan -> scatter
// ------------------------------------------------------------------
__global__ __launch_bounds__(256) void count_deg(const int* __restrict__ ei, int E, int E2,
                                                 int* __restrict__ counts)
{
    int e = blockIdx.x * 256 + threadIdx.x;
    if (e >= E2) return;
    int dd = (e < E) ? ei[E + e] : (e - E);
    atomicAdd(&counts[dd], 1);
}

// per-block exclusive scan (shfl) + block totals
__global__ __launch_bounds__(256) void scan1(const int* __restrict__ counts,
                                             int* __restrict__ offs,
                                             int* __restrict__ btot, int n)
{
    int b = blockIdx.x, tid = threadIdx.x, i = b * 256 + tid;
    int lane = tid & 63, w = tid >> 6;
    int v = (i < n) ? counts[i] : 0;
    int s = v;
#pragma unroll
    for (int o = 1; o < 64; o <<= 1) {
        int t = __shfl_up(s, o);
        if (lane >= o) s += t;
    }
    __shared__ int wsum[4];
    if (lane == 63) wsum[w] = s;
    __syncthreads();
    int base = 0;
#pragma unroll
    for (int k = 0; k < 4; ++k)
        if (k < w) base += wsum[k];
    int incl = s + base;
    if (i < n) offs[i] = incl - v;          // block-local exclusive
    if (tid == 255) btot[b] = incl;
}

// add prefix of block totals (in place); last block writes offs[n]
__global__ __launch_bounds__(256) void scan2(int* __restrict__ offs,
                                             const int* __restrict__ btot, int n)
{
    int b = blockIdx.x, tid = threadIdx.x, i = b * 256 + tid;
    __shared__ int sbase;
    if (tid < 64) {
        int v = (tid < b) ? btot[tid] : 0;   // gridDim <= 64
#pragma unroll
        for (int o = 32; o > 0; o >>= 1) v += __shfl_down(v, o);
        if (tid == 0) sbase = v;
    }
    __syncthreads();
    if (i < n) offs[i] += sbase;
    if (b == (int)gridDim.x - 1 && tid == 255) offs[n] = sbase + btot[b];
}

__global__ __launch_bounds__(256) void scatter_csr(const int* __restrict__ ei, int E, int E2,
                                                   const int* __restrict__ offsets,
                                                   int* __restrict__ cursor,
                                                   int* __restrict__ csr_src)
{
    int e = blockIdx.x * 256 + threadIdx.x;
    if (e >= E2) return;
    int s, dd;
    if (e < E) { s = ei[e]; dd = ei[E + e]; }
    else       { s = e - E; dd = e - E; }
    int pos = offsets[dd] + atomicAdd(&cursor[dd], 1);
    csr_src[pos] = s;
}

// ------------------------------------------------------------------
// Per-edge softmax weights, H=4. One wave per dst.
// lane = i0*4 + h  ->  alpha[(o0+i)*4+h] writes are contiguous per sweep.
// ------------------------------------------------------------------
__global__ __launch_bounds__(64) void alpha_h4(const float* __restrict__ a_s,
                                               const float* __restrict__ a_d,
                                               const int* __restrict__ offsets,
                                               const int* __restrict__ csr_src,
                                               float* __restrict__ alpha)
{
    const int dst = blockIdx.x;
    const int lane = threadIdx.x;
    const int o0 = offsets[dst];
    const int deg = offsets[dst + 1] - o0;
    const int h = lane & 3;
    const int i0 = lane >> 2;
    const float adh = a_d[dst * 4 + h];

    float m = -1e30f;
    for (int i = i0; i < deg; i += 16)
        m = fmaxf(m, lrelu(a_s[csr_src[o0 + i] * 4 + h] + adh));
#pragma unroll
    for (int o = 4; o < 64; o <<= 1) m = fmaxf(m, __shfl_xor(m, o));
    float sum = 0.f;
    for (int i = i0; i < deg; i += 16)
        sum += __expf(lrelu(a_s[csr_src[o0 + i] * 4 + h] + adh) - m);
#pragma unroll
    for (int o = 4; o < 64; o <<= 1) sum += __shfl_xor(sum, o);
    const float inv = 1.f / sum;
    for (int i = i0; i < deg; i += 16)
        alpha[(size_t)(o0 + i) * 4 + h] =
            __expf(lrelu(a_s[csr_src[o0 + i] * 4 + h] + adh) - m) * inv;
}

// Per-edge softmax weights, H=1. One wave per dst.
__global__ __launch_bounds__(64) void alpha_h1(const float* __restrict__ a_s,
                                               const float* __restrict__ a_d,
                                               const int* __restrict__ offsets,
                                               const int* __restrict__ csr_src,
                                               float* __restrict__ alpha)
{
    const int dst = blockIdx.x;
    const int lane = threadIdx.x;
    const int o0 = offsets[dst];
    const int deg = offsets[dst + 1] - o0;
    const float ad = a_d[dst];

    float m = -1e30f;
    for (int i = lane; i < deg; i += 64)
        m = fmaxf(m, lrelu(a_s[csr_src[o0 + i]] + ad));
#pragma unroll
    for (int o = 1; o < 64; o <<= 1) m = fmaxf(m, __shfl_xor(m, o));
    float sum = 0.f;
    for (int i = lane; i < deg; i += 64)
        sum += __expf(lrelu(a_s[csr_src[o0 + i]] + ad) - m);
#pragma unroll
    for (int o = 1; o < 64; o <<= 1) sum += __shfl_xor(sum, o);
    const float inv = 1.f / sum;
    for (int i = lane; i < deg; i += 64)
        alpha[o0 + i] = __expf(lrelu(a_s[csr_src[o0 + i]] + ad) - m) * inv;
}

// ------------------------------------------------------------------
// Gather H=4: one block (256 thr) per dst; pure alpha*row accumulate, x4 unroll.
// ------------------------------------------------------------------
__global__ __launch_bounds__(256) void gather_h4(const unsigned short* __restrict__ xl,
                                                 const float* __restrict__ alpha,
                                                 const int* __restrict__ offsets,
                                                 const int* __restrict__ csr_src,
                                                 const float* __restrict__ bias,
                                                 unsigned short* __restrict__ outb)
{
    const int dst = blockIdx.x;
    const int t = threadIdx.x;
    const int o0 = offsets[dst];
    const int deg = offsets[dst + 1] - o0;
    const int c4 = t * 4;
    const int h = t >> 6;

    float ax = 0.f, ay = 0.f, az = 0.f, aw = 0.f;
    int i = 0;
    for (; i + 4 <= deg; i += 4) {
        int p = o0 + i;
        int s0 = csr_src[p], s1 = csr_src[p + 1], s2 = csr_src[p + 2], s3 = csr_src[p + 3];
        float al0 = alpha[(size_t)p * 4 + h];
        float al1 = alpha[(size_t)(p + 1) * 4 + h];
        float al2 = alpha[(size_t)(p + 2) * 4 + h];
        float al3 = alpha[(size_t)(p + 3) * 4 + h];
        ushort4 v0 = *reinterpret_cast<const ushort4*>(xl + (size_t)s0 * 1024 + c4);
        ushort4 v1 = *reinterpret_cast<const ushort4*>(xl + (size_t)s1 * 1024 + c4);
        ushort4 v2 = *reinterpret_cast<const ushort4*>(xl + (size_t)s2 * 1024 + c4);
        ushort4 v3 = *reinterpret_cast<const ushort4*>(xl + (size_t)s3 * 1024 + c4);
        ax = fmaf(al0, bf2f(v0.x), ax); ay = fmaf(al0, bf2f(v0.y), ay);
        az = fmaf(al0, bf2f(v0.z), az); aw = fmaf(al0, bf2f(v0.w), aw);
        ax = fmaf(al1, bf2f(v1.x), ax); ay = fmaf(al1, bf2f(v1.y), ay);
        az = fmaf(al1, bf2f(v1.z), az); aw = fmaf(al1, bf2f(v1.w), aw);
        ax = fmaf(al2, bf2f(v2.x), ax); ay = fmaf(al2, bf2f(v2.y), ay);
        az = fmaf(al2, bf2f(v2.z), az); aw = fmaf(al2, bf2f(v2.w), aw);
        ax = fmaf(al3, bf2f(v3.x), ax); ay = fmaf(al3, bf2f(v3.y), ay);
        az = fmaf(al3, bf2f(v3.z), az); aw = fmaf(al3, bf2f(v3.w), aw);
    }
    for (; i < deg; ++i) {
        int p = o0 + i;
        int s = csr_src[p];
        float al = alpha[(size_t)p * 4 + h];
        ushort4 v = *reinterpret_cast<const ushort4*>(xl + (size_t)s * 1024 + c4);
        ax = fmaf(al, bf2f(v.x), ax); ay = fmaf(al, bf2f(v.y), ay);
        az = fmaf(al, bf2f(v.z), az); aw = fmaf(al, bf2f(v.w), aw);
    }
    float4 b = *reinterpret_cast<const float4*>(bias + c4);
    ushort4 r;
    r.x = f2bf(fmaxf(ax + b.x, 0.f));
    r.y = f2bf(fmaxf(ay + b.y, 0.f));
    r.z = f2bf(fmaxf(az + b.z, 0.f));
    r.w = f2bf(fmaxf(aw + b.w, 0.f));
    *reinterpret_cast<ushort4*>(outb + (size_t)dst * 1024 + c4) = r;
}

// ------------------------------------------------------------------
// Gather H=1: one wave per dst, x4 unroll, f32 out (+bias, relu).
// ------------------------------------------------------------------
__global__ __launch_bounds__(64) void gather_h1(const unsigned short* __restrict__ xl,
                                                const float* __restrict__ alpha,
                                                const int* __restrict__ offsets,
                                                const int* __restrict__ csr_src,
                                                const float* __restrict__ bias,
                                                float* __restrict__ outb)
{
    const int dst = blockIdx.x;
    const int lane = threadIdx.x;
    const int o0 = offsets[dst];
    const int deg = offsets[dst + 1] - o0;
    const int c4 = lane * 4;

    float ax = 0.f, ay = 0.f, az = 0.f, aw = 0.f;
    int i = 0;
    for (; i + 4 <= deg; i += 4) {
        int p = o0 + i;
        int s0 = csr_src[p], s1 = csr_src[p + 1], s2 = csr_src[p + 2], s3 = csr_src[p + 3];
        float al0 = alpha[p], al1 = alpha[p + 1], al2 = alpha[p + 2], al3 = alpha[p + 3];
        ushort4 v0 = *reinterpret_cast<const ushort4*>(xl + (size_t)s0 * 256 + c4);
        ushort4 v1 = *reinterpret_cast<const ushort4*>(xl + (size_t)s1 * 256 + c4);
        ushort4 v2 = *reinterpret_cast<const ushort4*>(xl + (size_t)s2 * 256 + c4);
        ushort4 v3 = *reinterpret_cast<const ushort4*>(xl + (size_t)s3 * 256 + c4);
        ax = fmaf(al0, bf2f(v0.x), ax); ay = fmaf(al0, bf2f(v0.y), ay);
        az = fmaf(al0, bf2f(v0.z), az); aw = fmaf(al0, bf2f(v0.w), aw);
        ax = fmaf(al1, bf2f(v1.x), ax); ay = fmaf(al1, bf2f(v1.y), ay);
        az = fmaf(al1, bf2f(v1.z), az); aw = fmaf(al1, bf2f(v1.w), aw);
        ax = fmaf(al2, bf2f(v2.x), ax); ay = fmaf(al2, bf2f(v2.y), ay);
        az = fmaf(al2, bf2f(v2.z), az); aw = fmaf(al2, bf2f(v2.w), aw);
        ax = fmaf(al3, bf2f(v3.x), ax); ay = fmaf(al3, bf2f(v3.y), ay);
        az = fmaf(al3, bf2f(v3.z), az); aw = fmaf(al3, bf2f(v3.w), aw);
    }
    for (; i < deg; ++i) {
        int p = o0 + i;
        int s = csr_src[p];
        float al = alpha[p];
        ushort4 v = *reinterpret_cast<const ushort4*>(xl + (size_t)s * 256 + c4);
        ax = fmaf(al, bf2f(v.x), ax); ay = fmaf(al, bf2f(v.y), ay);
        az = fmaf(al, bf2f(v.z), az); aw = fmaf(al, bf2f(v.w), aw);
    }
    float4 b = *reinterpret_cast<const float4*>(bias + c4);
    float4 r;
    r.x = fmaxf(ax + b.x, 0.f);
    r.y = fmaxf(ay + b.y, 0.f);
    r.z = fmaxf(az + b.z, 0.f);
    r.w = fmaxf(aw + b.w, 0.f);
    *reinterpret_cast<float4*>(outb + (size_t)dst * 256 + c4) = r;
}

// ------------------------------------------------------------------
__global__ __launch_bounds__(256) void mean_pool(const float* __restrict__ h2,
                                                 float* __restrict__ meanv, int N)
{
    int c = threadIdx.x;
    float s = 0.f;
    for (int r = blockIdx.x; r < N; r += gridDim.x)
        s += h2[(size_t)r * 256 + c];
    atomicAdd(&meanv[c], s);
}

__global__ __launch_bounds__(64) void final_k(const float* __restrict__ meanv,
                                              const float* __restrict__ Wc,
                                              const float* __restrict__ bc,
                                              float* __restrict__ out, int N, int NCLS)
{
    int k = threadIdx.x;
    if (k >= NCLS) return;
    float invN = 1.f / (float)N;
    float s = 0.f;
    for (int c = 0; c < 256; ++c)
        s = fmaf(meanv[c] * invN, Wc[c * NCLS + k], s);
    out[k] = s + bc[k];
}

// ------------------------------------------------------------------
extern "C" void kernel_launch(void* const* d_in, const int* in_sizes, int n_in,
                              void* d_out, int out_size, void* d_ws, size_t ws_size,
                              hipStream_t stream)
{
    const float* x   = (const float*)d_in[0];
    const int*   ei  = (const int*)d_in[1];
    const float* W1  = (const float*)d_in[2];
    const float* as1 = (const float*)d_in[3];
    const float* ad1 = (const float*)d_in[4];
    const float* b1  = (const float*)d_in[5];
    const float* W2  = (const float*)d_in[6];
    const float* as2 = (const float*)d_in[7];
    const float* ad2 = (const float*)d_in[8];
    const float* b2  = (const float*)d_in[9];
    const float* Wc  = (const float*)d_in[10];
    const float* bc  = (const float*)d_in[11];
    float* out = (float*)d_out;

    const int D = 128, H = 4, C = 256, HC = 1024;
    const int N = in_sizes[0] / D;              // 10000
    const int E = in_sizes[1] / 2;              // 160000
    const int E2 = E + N;
    const int NCLS = in_sizes[11];
    const int Mpad = ((N + 127) / 128) * 128;   // 10112
    const int NB = (N + 255) / 256;             // scan blocks (40 <= 64)

    char* ws = (char*)d_ws;
    size_t woff = 0;
    auto take = [&](size_t bytes) -> char* {
        char* p = ws + woff;
        woff += (bytes + 255) & ~(size_t)255;
        return p;
    };
    unsigned short* x_bf  = (unsigned short*)take((size_t)Mpad * D * 2);
    unsigned short* w1t   = (unsigned short*)take((size_t)HC * D * 2);
    unsigned short* w2t   = (unsigned short*)take((size_t)C * HC * 2);
    unsigned short* xl1   = (unsigned short*)take((size_t)Mpad * HC * 2);
    unsigned short* h1    = (unsigned short*)take((size_t)Mpad * HC * 2);
    unsigned short* xl2   = (unsigned short*)take((size_t)Mpad * C * 2);
    float* h2     = (float*)take((size_t)N * C * 4);
    float* a_s1   = (float*)take((size_t)N * H * 4);
    float* a_d1   = (float*)take((size_t)N * H * 4);
    float* a_s2   = (float*)take((size_t)N * 4);
    float* a_d2   = (float*)take((size_t)N * 4);
    float* alpha1 = (float*)take((size_t)E2 * H * 4);
    float* alpha2 = (float*)take((size_t)E2 * 4);
    int*   counts = (int*)take((size_t)N * 4);
    int*   cursor = (int*)take((size_t)N * 4);
    int*   offs   = (int*)take((size_t)(N + 1) * 4);
    int*   btot   = (int*)take(64 * 4);
    int*   csrsrc = (int*)take((size_t)E2 * 4);
    float* meanv  = (float*)take(256 * 4);

    hipMemsetAsync(counts, 0, (size_t)N * 4, stream);
    hipMemsetAsync(cursor, 0, (size_t)N * 4, stream);
    hipMemsetAsync(meanv, 0, 256 * 4, stream);
    if (Mpad > N)
        hipMemsetAsync(h1 + (size_t)N * HC, 0, (size_t)(Mpad - N) * HC * 2, stream);

    // Input conversions
    convert_pad<<<(Mpad * D / 4 + 255) / 256, 256, 0, stream>>>(x, x_bf, N * D / 4, Mpad * D / 4);
    transpose_cvt<<<dim3(HC / 32, D / 32), dim3(32, 8), 0, stream>>>(W1, w1t, D, HC);
    transpose_cvt<<<dim3(C / 32, HC / 32), dim3(32, 8), 0, stream>>>(W2, w2t, HC, C);

    // CSR build
    count_deg<<<(E2 + 255) / 256, 256, 0, stream>>>(ei, E, E2, counts);
    scan1<<<NB, 256, 0, stream>>>(counts, offs, btot, N);
    scan2<<<NB, 256, 0, stream>>>(offs, btot, N);
    scatter_csr<<<(E2 + 255) / 256, 256, 0, stream>>>(ei, E, E2, offs, cursor, csrsrc);

    // Layer 1
    gemm_bf16<<<dim3(HC / 128, Mpad / 128), 256, 0, stream>>>(x_bf, w1t, xl1, Mpad, HC, D);
    attn_scores<<<(N * H + 3) / 4, 256, 0, stream>>>(xl1, as1, ad1, a_s1, a_d1, N * H, H);
    alpha_h4<<<N, 64, 0, stream>>>(a_s1, a_d1, offs, csrsrc, alpha1);
    gather_h4<<<N, 256, 0, stream>>>(xl1, alpha1, offs, csrsrc, b1, h1);

    // Layer 2
    gemm_bf16<<<dim3(C / 128, Mpad / 128), 256, 0, stream>>>(h1, w2t, xl2, Mpad, C, HC);
    attn_scores<<<(N + 3) / 4, 256, 0, stream>>>(xl2, as2, ad2, a_s2, a_d2, N, 1);
    alpha_h1<<<N, 64, 0, stream>>>(a_s2, a_d2, offs, csrsrc, alpha2);
    gather_h1<<<N, 64, 0, stream>>>(xl2, alpha2, offs, csrsrc, b2, h2);

    // Pool + classifier
    mean_pool<<<40, 256, 0, stream>>>(h2, meanv, N);
    final_k<<<1, 64, 0, stream>>>(meanv, Wc, bc, out, N, NCLS);
}

// Round 4
// 266.358 us; speedup vs baseline: 1.8566x; 1.1470x over previous
//
#include <hip/hip_runtime.h>
#include <hip/hip_bf16.h>
#include <math.h>

#define NEG_SLOPE 0.2f

typedef __attribute__((ext_vector_type(8))) short short8;
typedef __attribute__((ext_vector_type(4))) float f32x4;

typedef __attribute__((address_space(1))) const void g_void;
typedef __attribute__((address_space(3))) void l_void;

__device__ __forceinline__ float lrelu(float x) { return x > 0.f ? x : NEG_SLOPE * x; }
__device__ __forceinline__ float bf2f(unsigned short u) { return __uint_as_float((unsigned)u << 16); }
__device__ __forceinline__ unsigned short f2bf(float f) {
    unsigned u = __float_as_uint(f);
    unsigned rounding = 0x7fff + ((u >> 16) & 1);
    return (unsigned short)((u + rounding) >> 16);
}

// ------------------------------------------------------------------
__global__ __launch_bounds__(256) void convert_pad(const float* __restrict__ in,
                                                   unsigned short* __restrict__ out,
                                                   int n_valid4, int n_total4)
{
    int g = blockIdx.x * 256 + threadIdx.x;
    if (g >= n_total4) return;
    ushort4 o;
    if (g < n_valid4) {
        float4 v = *reinterpret_cast<const float4*>(in + (size_t)g * 4);
        o = make_ushort4(f2bf(v.x), f2bf(v.y), f2bf(v.z), f2bf(v.w));
    } else {
        o = make_ushort4(0, 0, 0, 0);
    }
    *reinterpret_cast<ushort4*>(out + (size_t)g * 4) = o;
}

// ------------------------------------------------------------------
__global__ void transpose_cvt(const float* __restrict__ in, unsigned short* __restrict__ out,
                              int R, int Cc)
{
    __shared__ float tile[32][33];
    int c0 = blockIdx.x * 32, r0 = blockIdx.y * 32;
#pragma unroll
    for (int j = 0; j < 4; ++j)
        tile[threadIdx.y + j * 8][threadIdx.x] =
            in[(size_t)(r0 + threadIdx.y + j * 8) * Cc + c0 + threadIdx.x];
    __syncthreads();
#pragma unroll
    for (int j = 0; j < 4; ++j)
        out[(size_t)(c0 + threadIdx.y + j * 8) * R + r0 + threadIdx.x] =
            f2bf(tile[threadIdx.x][threadIdx.y + j * 8]);
}

// ------------------------------------------------------------------
// bf16 MFMA GEMM: C = A @ Bt^T, 128x128, BK=64.
// ------------------------------------------------------------------
__global__ __launch_bounds__(256) void gemm_bf16(const unsigned short* __restrict__ A,
                                                 const unsigned short* __restrict__ Bt,
                                                 unsigned short* __restrict__ C,
                                                 int M, int Nc, int K)
{
    __shared__ unsigned short sA[128 * 64];
    __shared__ unsigned short sB[128 * 64];
    const int tid = threadIdx.x;
    const int lane = tid & 63;
    const int w = tid >> 6;
    const int wr = w >> 1, wc = w & 1;
    const int m0 = blockIdx.y * 128;
    const int n0 = blockIdx.x * 128;

    f32x4 acc[4][4];
#pragma unroll
    for (int i = 0; i < 4; ++i)
#pragma unroll
        for (int j = 0; j < 4; ++j) acc[i][j] = (f32x4){0.f, 0.f, 0.f, 0.f};

    const int lrow = lane >> 3;
    const int lchunk = (lane & 7) ^ lrow;

    for (int k0 = 0; k0 < K; k0 += 64) {
#pragma unroll
        for (int i = 0; i < 4; ++i) {
            int r0 = (w * 4 + i) * 8;
            const unsigned short* g = A + (size_t)(m0 + r0 + lrow) * K + k0 + lchunk * 8;
            __builtin_amdgcn_global_load_lds((g_void*)g, (l_void*)((char*)sA + r0 * 128), 16, 0, 0);
        }
#pragma unroll
        for (int i = 0; i < 4; ++i) {
            int r0 = (w * 4 + i) * 8;
            const unsigned short* g = Bt + (size_t)(n0 + r0 + lrow) * K + k0 + lchunk * 8;
            __builtin_amdgcn_global_load_lds((g_void*)g, (l_void*)((char*)sB + r0 * 128), 16, 0, 0);
        }
        __syncthreads();
#pragma unroll
        for (int kk = 0; kk < 2; ++kk) {
            short8 a[4], b[4];
#pragma unroll
            for (int i = 0; i < 4; ++i) {
                int r = wr * 64 + i * 16 + (lane & 15);
                int sw = (kk * 4 + (lane >> 4)) ^ (r & 7);
                a[i] = *reinterpret_cast<const short8*>(&sA[r * 64 + sw * 8]);
            }
#pragma unroll
            for (int j = 0; j < 4; ++j) {
                int r = wc * 64 + j * 16 + (lane & 15);
                int sw = (kk * 4 + (lane >> 4)) ^ (r & 7);
                b[j] = *reinterpret_cast<const short8*>(&sB[r * 64 + sw * 8]);
            }
#pragma unroll
            for (int i = 0; i < 4; ++i)
#pragma unroll
                for (int j = 0; j < 4; ++j)
                    acc[i][j] = __builtin_amdgcn_mfma_f32_16x16x32_bf16(a[i], b[j], acc[i][j], 0, 0, 0);
        }
        __syncthreads();
    }

#pragma unroll
    for (int i = 0; i < 4; ++i) {
        int row_b = m0 + wr * 64 + i * 16 + (lane >> 4) * 4;
#pragma unroll
        for (int j = 0; j < 4; ++j) {
            int col = n0 + wc * 64 + j * 16 + (lane & 15);
#pragma unroll
            for (int r = 0; r < 4; ++r)
                C[(size_t)(row_b + r) * Nc + col] = f2bf(acc[i][j][r]);
        }
    }
}

// ------------------------------------------------------------------
__global__ __launch_bounds__(256) void attn_scores(const unsigned short* __restrict__ xl,
                                                   const float* __restrict__ att_s,
                                                   const float* __restrict__ att_d,
                                                   float* __restrict__ a_s,
                                                   float* __restrict__ a_d,
                                                   int NH, int H)
{
    int wid = (blockIdx.x * 256 + threadIdx.x) >> 6;
    int lane = threadIdx.x & 63;
    if (wid >= NH) return;
    int h = wid % H;
    ushort4 v = *reinterpret_cast<const ushort4*>(xl + (size_t)wid * 256 + lane * 4);
    float4 vs = *reinterpret_cast<const float4*>(att_s + h * 256 + lane * 4);
    float4 vd = *reinterpret_cast<const float4*>(att_d + h * 256 + lane * 4);
    float x0 = bf2f(v.x), x1 = bf2f(v.y), x2 = bf2f(v.z), x3 = bf2f(v.w);
    float ss = x0 * vs.x + x1 * vs.y + x2 * vs.z + x3 * vs.w;
    float sd = x0 * vd.x + x1 * vd.y + x2 * vd.z + x3 * vd.w;
#pragma unroll
    for (int o = 32; o > 0; o >>= 1) {
        ss += __shfl_down(ss, o);
        sd += __shfl_down(sd, o);
    }
    if (lane == 0) { a_s[wid] = ss; a_d[wid] = sd; }
}

// ------------------------------------------------------------------
// CSR: count -> 2-kernel scan -> scatter
// ------------------------------------------------------------------
__global__ __launch_bounds__(256) void count_deg(const int* __restrict__ ei, int E, int E2,
                                                 int* __restrict__ counts)
{
    int e = blockIdx.x * 256 + threadIdx.x;
    if (e >= E2) return;
    int dd = (e < E) ? ei[E + e] : (e - E);
    atomicAdd(&counts[dd], 1);
}

__global__ __launch_bounds__(256) void scan1(const int* __restrict__ counts,
                                             int* __restrict__ offs,
                                             int* __restrict__ btot, int n)
{
    int b = blockIdx.x, tid = threadIdx.x, i = b * 256 + tid;
    int lane = tid & 63, w = tid >> 6;
    int v = (i < n) ? counts[i] : 0;
    int s = v;
#pragma unroll
    for (int o = 1; o < 64; o <<= 1) {
        int t = __shfl_up(s, o);
        if (lane >= o) s += t;
    }
    __shared__ int wsum[4];
    if (lane == 63) wsum[w] = s;
    __syncthreads();
    int base = 0;
#pragma unroll
    for (int k = 0; k < 4; ++k)
        if (k < w) base += wsum[k];
    int incl = s + base;
    if (i < n) offs[i] = incl - v;
    if (tid == 255) btot[b] = incl;
}

__global__ __launch_bounds__(256) void scan2(int* __restrict__ offs,
                                             const int* __restrict__ btot, int n)
{
    int b = blockIdx.x, tid = threadIdx.x, i = b * 256 + tid;
    __shared__ int sbase;
    if (tid < 64) {
        int v = (tid < b) ? btot[tid] : 0;
#pragma unroll
        for (int o = 32; o > 0; o >>= 1) v += __shfl_down(v, o);
        if (tid == 0) sbase = v;
    }
    __syncthreads();
    if (i < n) offs[i] += sbase;
    if (b == (int)gridDim.x - 1 && tid == 255) offs[n] = sbase + btot[b];
}

__global__ __launch_bounds__(256) void scatter_csr(const int* __restrict__ ei, int E, int E2,
                                                   const int* __restrict__ offsets,
                                                   int* __restrict__ cursor,
                                                   int* __restrict__ csr_src)
{
    int e = blockIdx.x * 256 + threadIdx.x;
    if (e >= E2) return;
    int s, dd;
    if (e < E) { s = ei[e]; dd = ei[E + e]; }
    else       { s = e - E; dd = e - E; }
    int pos = offsets[dd] + atomicAdd(&cursor[dd], 1);
    csr_src[pos] = s;
}

// ------------------------------------------------------------------
__global__ __launch_bounds__(64) void alpha_h4(const float* __restrict__ a_s,
                                               const float* __restrict__ a_d,
                                               const int* __restrict__ offsets,
                                               const int* __restrict__ csr_src,
                                               float* __restrict__ alpha)
{
    const int dst = blockIdx.x;
    const int lane = threadIdx.x;
    const int o0 = offsets[dst];
    const int deg = offsets[dst + 1] - o0;
    const int h = lane & 3;
    const int i0 = lane >> 2;
    const float adh = a_d[dst * 4 + h];

    float m = -1e30f;
    for (int i = i0; i < deg; i += 16)
        m = fmaxf(m, lrelu(a_s[csr_src[o0 + i] * 4 + h] + adh));
#pragma unroll
    for (int o = 4; o < 64; o <<= 1) m = fmaxf(m, __shfl_xor(m, o));
    float sum = 0.f;
    for (int i = i0; i < deg; i += 16)
        sum += __expf(lrelu(a_s[csr_src[o0 + i] * 4 + h] + adh) - m);
#pragma unroll
    for (int o = 4; o < 64; o <<= 1) sum += __shfl_xor(sum, o);
    const float inv = 1.f / sum;
    for (int i = i0; i < deg; i += 16)
        alpha[(size_t)(o0 + i) * 4 + h] =
            __expf(lrelu(a_s[csr_src[o0 + i] * 4 + h] + adh) - m) * inv;
}

__global__ __launch_bounds__(64) void alpha_h1(const float* __restrict__ a_s,
                                               const float* __restrict__ a_d,
                                               const int* __restrict__ offsets,
                                               const int* __restrict__ csr_src,
                                               float* __restrict__ alpha)
{
    const int dst = blockIdx.x;
    const int lane = threadIdx.x;
    const int o0 = offsets[dst];
    const int deg = offsets[dst + 1] - o0;
    const float ad = a_d[dst];

    float m = -1e30f;
    for (int i = lane; i < deg; i += 64)
        m = fmaxf(m, lrelu(a_s[csr_src[o0 + i]] + ad));
#pragma unroll
    for (int o = 1; o < 64; o <<= 1) m = fmaxf(m, __shfl_xor(m, o));
    float sum = 0.f;
    for (int i = lane; i < deg; i += 64)
        sum += __expf(lrelu(a_s[csr_src[o0 + i]] + ad) - m);
#pragma unroll
    for (int o = 1; o < 64; o <<= 1) sum += __shfl_xor(sum, o);
    const float inv = 1.f / sum;
    for (int i = lane; i < deg; i += 64)
        alpha[o0 + i] = __expf(lrelu(a_s[csr_src[o0 + i]] + ad) - m) * inv;
}

// ------------------------------------------------------------------
__global__ __launch_bounds__(256) void gather_h4(const unsigned short* __restrict__ xl,
                                                 const float* __restrict__ alpha,
                                                 const int* __restrict__ offsets,
                                                 const int* __restrict__ csr_src,
                                                 const float* __restrict__ bias,
                                                 unsigned short* __restrict__ outb)
{
    const int dst = blockIdx.x;
    const int t = threadIdx.x;
    const int o0 = offsets[dst];
    const int deg = offsets[dst + 1] - o0;
    const int c4 = t * 4;
    const int h = t >> 6;

    float ax = 0.f, ay = 0.f, az = 0.f, aw = 0.f;
    int i = 0;
    for (; i + 4 <= deg; i += 4) {
        int p = o0 + i;
        int s0 = csr_src[p], s1 = csr_src[p + 1], s2 = csr_src[p + 2], s3 = csr_src[p + 3];
        float al0 = alpha[(size_t)p * 4 + h];
        float al1 = alpha[(size_t)(p + 1) * 4 + h];
        float al2 = alpha[(size_t)(p + 2) * 4 + h];
        float al3 = alpha[(size_t)(p + 3) * 4 + h];
        ushort4 v0 = *reinterpret_cast<const ushort4*>(xl + (size_t)s0 * 1024 + c4);
        ushort4 v1 = *reinterpret_cast<const ushort4*>(xl + (size_t)s1 * 1024 + c4);
        ushort4 v2 = *reinterpret_cast<const ushort4*>(xl + (size_t)s2 * 1024 + c4);
        ushort4 v3 = *reinterpret_cast<const ushort4*>(xl + (size_t)s3 * 1024 + c4);
        ax = fmaf(al0, bf2f(v0.x), ax); ay = fmaf(al0, bf2f(v0.y), ay);
        az = fmaf(al0, bf2f(v0.z), az); aw = fmaf(al0, bf2f(v0.w), aw);
        ax = fmaf(al1, bf2f(v1.x), ax); ay = fmaf(al1, bf2f(v1.y), ay);
        az = fmaf(al1, bf2f(v1.z), az); aw = fmaf(al1, bf2f(v1.w), aw);
        ax = fmaf(al2, bf2f(v2.x), ax); ay = fmaf(al2, bf2f(v2.y), ay);
        az = fmaf(al2, bf2f(v2.z), az); aw = fmaf(al2, bf2f(v2.w), aw);
        ax = fmaf(al3, bf2f(v3.x), ax); ay = fmaf(al3, bf2f(v3.y), ay);
        az = fmaf(al3, bf2f(v3.z), az); aw = fmaf(al3, bf2f(v3.w), aw);
    }
    for (; i < deg; ++i) {
        int p = o0 + i;
        int s = csr_src[p];
        float al = alpha[(size_t)p * 4 + h];
        ushort4 v = *reinterpret_cast<const ushort4*>(xl + (size_t)s * 1024 + c4);
        ax = fmaf(al, bf2f(v.x), ax); ay = fmaf(al, bf2f(v.y), ay);
        az = fmaf(al, bf2f(v.z), az); aw = fmaf(al, bf2f(v.w), aw);
    }
    float4 b = *reinterpret_cast<const float4*>(bias + c4);
    ushort4 r;
    r.x = f2bf(fmaxf(ax + b.x, 0.f));
    r.y = f2bf(fmaxf(ay + b.y, 0.f));
    r.z = f2bf(fmaxf(az + b.z, 0.f));
    r.w = f2bf(fmaxf(aw + b.w, 0.f));
    *reinterpret_cast<ushort4*>(outb + (size_t)dst * 1024 + c4) = r;
}

// ------------------------------------------------------------------
__global__ __launch_bounds__(64) void gather_h1(const unsigned short* __restrict__ xl,
                                                const float* __restrict__ alpha,
                                                const int* __restrict__ offsets,
                                                const int* __restrict__ csr_src,
                                                const float* __restrict__ bias,
                                                float* __restrict__ outb)
{
    const int dst = blockIdx.x;
    const int lane = threadIdx.x;
    const int o0 = offsets[dst];
    const int deg = offsets[dst + 1] - o0;
    const int c4 = lane * 4;

    float ax = 0.f, ay = 0.f, az = 0.f, aw = 0.f;
    int i = 0;
    for (; i + 4 <= deg; i += 4) {
        int p = o0 + i;
        int s0 = csr_src[p], s1 = csr_src[p + 1], s2 = csr_src[p + 2], s3 = csr_src[p + 3];
        float al0 = alpha[p], al1 = alpha[p + 1], al2 = alpha[p + 2], al3 = alpha[p + 3];
        ushort4 v0 = *reinterpret_cast<const ushort4*>(xl + (size_t)s0 * 256 + c4);
        ushort4 v1 = *reinterpret_cast<const ushort4*>(xl + (size_t)s1 * 256 + c4);
        ushort4 v2 = *reinterpret_cast<const ushort4*>(xl + (size_t)s2 * 256 + c4);
        ushort4 v3 = *reinterpret_cast<const ushort4*>(xl + (size_t)s3 * 256 + c4);
        ax = fmaf(al0, bf2f(v0.x), ax); ay = fmaf(al0, bf2f(v0.y), ay);
        az = fmaf(al0, bf2f(v0.z), az); aw = fmaf(al0, bf2f(v0.w), aw);
        ax = fmaf(al1, bf2f(v1.x), ax); ay = fmaf(al1, bf2f(v1.y), ay);
        az = fmaf(al1, bf2f(v1.z), az); aw = fmaf(al1, bf2f(v1.w), aw);
        ax = fmaf(al2, bf2f(v2.x), ax); ay = fmaf(al2, bf2f(v2.y), ay);
        az = fmaf(al2, bf2f(v2.z), az); aw = fmaf(al2, bf2f(v2.w), aw);
        ax = fmaf(al3, bf2f(v3.x), ax); ay = fmaf(al3, bf2f(v3.y), ay);
        az = fmaf(al3, bf2f(v3.z), az); aw = fmaf(al3, bf2f(v3.w), aw);
    }
    for (; i < deg; ++i) {
        int p = o0 + i;
        int s = csr_src[p];
        float al = alpha[p];
        ushort4 v = *reinterpret_cast<const ushort4*>(xl + (size_t)s * 256 + c4);
        ax = fmaf(al, bf2f(v.x), ax); ay = fmaf(al, bf2f(v.y), ay);
        az = fmaf(al, bf2f(v.z), az); aw = fmaf(al, bf2f(v.w), aw);
    }
    float4 b = *reinterpret_cast<const float4*>(bias + c4);
    float4 r;
    r.x = fmaxf(ax + b.x, 0.f);
    r.y = fmaxf(ay + b.y, 0.f);
    r.z = fmaxf(az + b.z, 0.f);
    r.w = fmaxf(aw + b.w, 0.f);
    *reinterpret_cast<float4*>(outb + (size_t)dst * 256 + c4) = r;
}

// ------------------------------------------------------------------
// Mean pool: 640 blocks grid-stride over rows; one atomicAdd per thread.
__global__ __launch_bounds__(256) void mean_pool(const float* __restrict__ h2,
                                                 float* __restrict__ meanv, int N)
{
    int c = threadIdx.x;
    float s = 0.f;
    for (int r = blockIdx.x; r < N; r += gridDim.x)
        s += h2[(size_t)r * 256 + c];
    atomicAdd(&meanv[c], s);
}

__global__ __launch_bounds__(64) void final_k(const float* __restrict__ meanv,
                                              const float* __restrict__ Wc,
                                              const float* __restrict__ bc,
                                              float* __restrict__ out, int N, int NCLS)
{
    int k = threadIdx.x;
    if (k >= NCLS) return;
    float invN = 1.f / (float)N;
    float s = 0.f;
    for (int c = 0; c < 256; ++c)
        s = fmaf(meanv[c] * invN, Wc[c * NCLS + k], s);
    out[k] = s + bc[k];
}

// ------------------------------------------------------------------
extern "C" void kernel_launch(void* const* d_in, const int* in_sizes, int n_in,
                              void* d_out, int out_size, void* d_ws, size_t ws_size,
                              hipStream_t stream)
{
    const float* x   = (const float*)d_in[0];
    const int*   ei  = (const int*)d_in[1];
    const float* W1  = (const float*)d_in[2];
    const float* as1 = (const float*)d_in[3];
    const float* ad1 = (const float*)d_in[4];
    const float* b1  = (const float*)d_in[5];
    const float* W2  = (const float*)d_in[6];
    const float* as2 = (const float*)d_in[7];
    const float* ad2 = (const float*)d_in[8];
    const float* b2  = (const float*)d_in[9];
    const float* Wc  = (const float*)d_in[10];
    const float* bc  = (const float*)d_in[11];
    float* out = (float*)d_out;

    const int D = 128, H = 4, C = 256, HC = 1024;
    const int N = in_sizes[0] / D;              // 10000
    const int E = in_sizes[1] / 2;              // 160000
    const int E2 = E + N;
    const int NCLS = in_sizes[11];
    const int Mpad = ((N + 127) / 128) * 128;   // 10112
    const int NB = (N + 255) / 256;             // scan blocks (40 <= 64)

    char* ws = (char*)d_ws;
    size_t woff = 0;
    auto take = [&](size_t bytes) -> char* {
        char* p = ws + woff;
        woff += (bytes + 255) & ~(size_t)255;
        return p;
    };
    unsigned short* x_bf  = (unsigned short*)take((size_t)Mpad * D * 2);
    unsigned short* w1t   = (unsigned short*)take((size_t)HC * D * 2);
    unsigned short* w2t   = (unsigned short*)take((size_t)C * HC * 2);
    unsigned short* xl1   = (unsigned short*)take((size_t)Mpad * HC * 2);
    unsigned short* h1    = (unsigned short*)take((size_t)Mpad * HC * 2);
    unsigned short* xl2   = (unsigned short*)take((size_t)Mpad * C * 2);
    float* h2     = (float*)take((size_t)N * C * 4);
    float* a_s1   = (float*)take((size_t)N * H * 4);
    float* a_d1   = (float*)take((size_t)N * H * 4);
    float* a_s2   = (float*)take((size_t)N * 4);
    float* a_d2   = (float*)take((size_t)N * 4);
    float* alpha1 = (float*)take((size_t)E2 * H * 4);
    float* alpha2 = (float*)take((size_t)E2 * 4);
    int*   counts = (int*)take((size_t)N * 4);
    int*   cursor = (int*)take((size_t)N * 4);
    int*   offs   = (int*)take((size_t)(N + 1) * 4);
    int*   btot   = (int*)take(64 * 4);
    int*   csrsrc = (int*)take((size_t)E2 * 4);
    float* meanv  = (float*)take(256 * 4);

    hipMemsetAsync(counts, 0, (size_t)N * 4, stream);
    hipMemsetAsync(cursor, 0, (size_t)N * 4, stream);
    hipMemsetAsync(meanv, 0, 256 * 4, stream);
    if (Mpad > N)
        hipMemsetAsync(h1 + (size_t)N * HC, 0, (size_t)(Mpad - N) * HC * 2, stream);

    // Input conversions
    convert_pad<<<(Mpad * D / 4 + 255) / 256, 256, 0, stream>>>(x, x_bf, N * D / 4, Mpad * D / 4);
    transpose_cvt<<<dim3(HC / 32, D / 32), dim3(32, 8), 0, stream>>>(W1, w1t, D, HC);
    transpose_cvt<<<dim3(C / 32, HC / 32), dim3(32, 8), 0, stream>>>(W2, w2t, HC, C);

    // CSR build
    count_deg<<<(E2 + 255) / 256, 256, 0, stream>>>(ei, E, E2, counts);
    scan1<<<NB, 256, 0, stream>>>(counts, offs, btot, N);
    scan2<<<NB, 256, 0, stream>>>(offs, btot, N);
    scatter_csr<<<(E2 + 255) / 256, 256, 0, stream>>>(ei, E, E2, offs, cursor, csrsrc);

    // Layer 1
    gemm_bf16<<<dim3(HC / 128, Mpad / 128), 256, 0, stream>>>(x_bf, w1t, xl1, Mpad, HC, D);
    attn_scores<<<(N * H + 3) / 4, 256, 0, stream>>>(xl1, as1, ad1, a_s1, a_d1, N * H, H);
    alpha_h4<<<N, 64, 0, stream>>>(a_s1, a_d1, offs, csrsrc, alpha1);
    gather_h4<<<N, 256, 0, stream>>>(xl1, alpha1, offs, csrsrc, b1, h1);

    // Layer 2
    gemm_bf16<<<dim3(C / 128, Mpad / 128), 256, 0, stream>>>(h1, w2t, xl2, Mpad, C, HC);
    attn_scores<<<(N + 3) / 4, 256, 0, stream>>>(xl2, as2, ad2, a_s2, a_d2, N, 1);
    alpha_h1<<<N, 64, 0, stream>>>(a_s2, a_d2, offs, csrsrc, alpha2);
    gather_h1<<<N, 64, 0, stream>>>(xl2, alpha2, offs, csrsrc, b2, h2);

    // Pool + classifier
    mean_pool<<<640, 256, 0, stream>>>(h2, meanv, N);
    final_k<<<1, 64, 0, stream>>>(meanv, Wc, bc, out, N, NCLS);
}